// Round 6
// baseline (221.809 us; speedup 1.0000x reference)
//
#include <hip/hip_runtime.h>
#include <stdint.h>

constexpr int kN = 16384;
constexpr int kD = 256;
constexpr int TM = 256, TN = 256;   // block tile 256x256
constexpr int KB = kD / 2;          // fp4 row = 128 bytes

using floatx16 = __attribute__((ext_vector_type(16))) float;  // 32x32 MFMA C/D
using floatx2  = __attribute__((ext_vector_type(2))) float;   // v_pk_* pair
using intx2v   = __attribute__((ext_vector_type(2))) int;
using intx4    = __attribute__((ext_vector_type(4))) int;
using intx8    = __attribute__((ext_vector_type(8))) int;     // f8f6f4 operand

// fp32*16 -> fp4 e2m1 RNE. Codes 0..7 = {0,.5,1,1.5,2,3,4,6} ARE the bit
// patterns (monotone). Thresholds are the RNE midpoints. (R12-verified.)
__device__ __forceinline__ uint32_t q4(float x) {
    float y = fabsf(x * 16.f);
    uint32_t c = (y >= 0.25f) + (y >= 0.75f) + (y >= 1.25f) + (y >= 1.75f)
               + (y >= 2.5f)  + (y >= 3.5f)  + (y >= 5.0f);
    return c | (x < 0.f ? 8u : 0u);
}

// 8 elems -> one dword per matrix per thread (nibble i = elem 8*idx+i).
// Also zeroes the loss accumulator (replaces the memset dispatch).
__global__ __launch_bounds__(256)
void cvt_fp4_kernel(const float* __restrict__ a, const float* __restrict__ b,
                    unsigned int* __restrict__ oa, unsigned int* __restrict__ ob,
                    float* __restrict__ out) {
    int idx = blockIdx.x * 256 + threadIdx.x;
    if (idx == 0) *out = 0.f;
    float4 a0 = *(const float4*)(a + (size_t)idx * 8);
    float4 a1 = *(const float4*)(a + (size_t)idx * 8 + 4);
    float4 b0 = *(const float4*)(b + (size_t)idx * 8);
    float4 b1 = *(const float4*)(b + (size_t)idx * 8 + 4);
    uint32_t pa = q4(a0.x) | (q4(a0.y) << 4) | (q4(a0.z) << 8)  | (q4(a0.w) << 12)
                | (q4(a1.x) << 16) | (q4(a1.y) << 20) | (q4(a1.z) << 24) | (q4(a1.w) << 28);
    uint32_t pb = q4(b0.x) | (q4(b0.y) << 4) | (q4(b0.z) << 8)  | (q4(b0.w) << 12)
                | (q4(b1.x) << 16) | (q4(b1.y) << 20) | (q4(b1.z) << 24) | (q4(b1.w) << 28);
    oa[idx] = pa;
    ob[idx] = pb;
}

// Undef-high 8-reg tuple from one 4-reg quad: fp4 MFMA reads only v[0:3]
// (HW-validated R14/R15: absmax 0.0). No adjacency constraint, no movs.
#define U8(v)  __builtin_shufflevector((v), (v), 0, 1, 2, 3, -1, -1, -1, -1)
#define MFMA4(a, b, c) __builtin_amdgcn_mfma_scale_f32_32x32x64_f8f6f4( \
        (a), (b), (c), 4 /*cbsz fp4*/, 4 /*blgp fp4*/, 0, 127, 0, 127)

// R19: R15 geometry (512thr, 128x64 wave-tile, phase-separated E/M, single
// acc[2][2] reused h0/h1 -- proven no-spill, 48.6us) + the three stall fixes
// R18's failure isolated:
//  (1) B double-buffer blA/blB: tile s+2 loads issue after tile s's last
//      MFMA reader -> ~2300cy prefetch distance >> L2 latency. Loads write
//      buffer regs DIRECTLY (no staging temps).
//  (2) operands stored as raw intx4 quads; every MFMA operand is U8(quad)
//      (undef high half) -> no CAT8/ROT8 movs, no lo/hi pairing constraint.
//  (3) SIMD-mates are waves w and w+4 (wr 0/1): s_sleep anti-phases them so
//      one wave's epilogue VALU rides under the other's MFMA drain.
// Budget: af 64 + bl 64 + z16 16 + acc 64(AGPR) + misc ~30 = ~238 < 256.
// Gate: WRITE_SIZE ~KB / FETCH ~10MB (no spill), then MfmaUtil 28 -> 40-50%.
__global__ __launch_bounds__(512, 2)
void siglip_gemm_loss_kernel(const unsigned char* __restrict__ A,   // fp4 [N][KB]
                             const unsigned char* __restrict__ B,   // fp4 [N][KB]
                             const float* __restrict__ scale_p,
                             const float* __restrict__ bias_p,
                             float* __restrict__ out) {
    __shared__ float red[8];

    const int tid  = threadIdx.x;
    const int wave = tid >> 6;     // 0..7
    const int lane = tid & 63;

    const int g    = blockIdx.x;                  // 256 persistent blocks
    const int tRow = ((g & 7) << 3) + (g >> 5);   // fixed tile-row (A-stripe L2-hot)
    const int sCol = (g >> 3) & 3;                // tile s -> col sCol + 4s

    const int wr = wave >> 2, wc = wave & 3;   // 2x4 waves
    const int m0 = wr * 128, n0 = wc * 64;     // wave tile 128x64
    const int l31 = lane & 31;
    const int h   = lane >> 5;                 // K-half: byte offset 16h

    // SIMD-mates (w, w+4) differ in wr: offset their phase by ~640cy so the
    // M/E phases interleave instead of colliding.
    if (wr) __builtin_amdgcn_s_sleep(10);

    const float sc  = *scale_p * (1.0f / 256.0f);   // undo x16 x16 prescale
    const float bs  = *bias_p;
    const float sc3 = sc * (1.44269504f * 8388608.0f);
    const float bs3 = fmaf(bs, 1.44269504f * 8388608.0f, 1064986823.0f);
    const floatx2 sc3v = (floatx2)(sc3);
    const floatx2 bs3v = (floatx2)(bs3);

    // ---- A operand: loop-invariant, resident as raw intx4 quads.
    // af[i][q] = bytes q*32 + 16h of row (tRow*TM + m0 + i*32 + l31).
    intx4 af[4][4];
    #pragma unroll
    for (int i = 0; i < 4; ++i) {
        const unsigned char* pa = A + ((size_t)tRow * TM + m0 + i * 32 + l31) * KB + 16 * h;
        #pragma unroll
        for (int q = 0; q < 4; ++q)
            af[i][q] = *(const intx4*)(pa + q * 32);
    }

    const floatx16 z16 = (floatx16)(0.f);   // C operand of each half's first MFMA

    floatx16 acc[2][2];     // ONE half-tile of accumulators, reused h0/h1
    floatx2 sm0 = (floatx2)(0.f), sm1 = (floatx2)(0.f);
    float smd = 0.f;        // diagonal correction accumulator

    // B addressing: walking uniform base (SGPR) + 32-bit voffsets.
    const unsigned char* pb = B + (size_t)sCol * TN * KB;
    const int voff0 = (n0 + l31) * KB + 16 * h;         // j = 0 rows
    const int voff1 = voff0 + 32 * KB;                  // j = 1 rows
    const size_t tStride = (size_t)4 * TN * KB;         // tile col advances by 4

    intx4 blA[2][4], blB[2][4];     // double-buffered B tiles (raw quads)

    auto loadT = [&](intx4 (&bl)[2][4]) {
        #pragma unroll
        for (int j = 0; j < 2; ++j) {
            const int vo = j ? voff1 : voff0;
            #pragma unroll
            for (int q = 0; q < 4; ++q)
                bl[j][q] = *(const intx4*)(pb + vo + q * 32);
        }
        pb += tStride;
    };

    // 16 MFMAs of one row-half (rows ibase..ibase+1). q-outer order gives 4
    // independent chains (ii x j) of length 4. First chunk takes C = z16.
    auto mfmaH = [&](const intx4 (&bq)[2][4], const int ibase) {
        #pragma unroll
        for (int q = 0; q < 4; ++q) {
            #pragma unroll
            for (int ii = 0; ii < 2; ++ii) {
                const intx8 a = U8(af[ibase + ii][q]);
                #pragma unroll
                for (int j = 0; j < 2; ++j)
                    acc[ii][j] = MFMA4(a, U8(bq[j][q]),
                                       q == 0 ? z16 : acc[ii][j]);
            }
        }
    };

    // Schraudolph epilogue of one half (64 elems), packed 2-wide.
    auto epiH = [&](const int ibase, const int tCol) {
        #pragma unroll
        for (int ii = 0; ii < 2; ++ii)
            #pragma unroll
            for (int j = 0; j < 2; ++j) {
                const floatx16 a = acc[ii][j];
                #pragma unroll
                for (int v = 0; v < 16; v += 4) {
                    floatx2 t0 = {a[v + 0], a[v + 1]};
                    floatx2 t1 = {a[v + 2], a[v + 3]};
                    t0 = __builtin_elementwise_fma(t0, sc3v, bs3v);  // v_pk_fma_f32
                    t1 = __builtin_elementwise_fma(t1, sc3v, bs3v);
                    const intx2v e0 = {(int)t0.x, (int)t0.y};        // v_cvt_i32_f32
                    const intx2v e1 = {(int)t1.x, (int)t1.y};
                    sm0 += __builtin_bit_cast(floatx2, e0);          // v_pk_add_f32
                    sm1 += __builtin_bit_cast(floatx2, e1);
                }
                // diagonal correction: term_diag = term_off - t
                const int gRow0 = tRow * TM + m0 + (ibase + ii) * 32;
                const int gCol0 = tCol * TN + n0 + j * 32;
                if (gRow0 == gCol0) {   // wave-uniform, rare
                    #pragma unroll
                    for (int v = 0; v < 16; ++v) {
                        const int rrow = (v & 3) + 8 * (v >> 2) + 4 * h;
                        if (rrow == l31) smd += fmaf(a[v], sc, bs);
                    }
                }
            }
    };

    // ---- pipelined main loop: B dbuf, phase-separated E/M (R15 shape).
    loadT(blA);                     // tile 0
    loadT(blB);                     // tile 1 (in flight across tile 0)
    mfmaH(blA, 0);                  // M h0(0)
    epiH(0, sCol);                  // E h0(0)
    mfmaH(blA, 2);                  // M h1(0)
    loadT(blA);                     // tile 2 into freed buffer
    for (int s = 1; s < 16; ++s) {
        const intx4 (&cur)[2][4] = (s & 1) ? blB : blA;
        const int cPrev = sCol + 4 * (s - 1);
        epiH(2, cPrev);             // E h1(s-1)
        mfmaH(cur, 0);              // M h0(s)
        epiH(0, cPrev + 4);         // E h0(s)
        mfmaH(cur, 2);              // M h1(s)
        if (s < 14) loadT((s & 1) ? blB : blA);   // tile s+2 into freed buffer
    }
    epiH(2, sCol + 60);             // drain tile 15 h1

    float sum = (sm0.x + sm1.x) + (sm0.y + sm1.y) - smd;

    // block reduce -> ONE atomicAdd per block (256 total, spread in time)
    #pragma unroll
    for (int off = 32; off > 0; off >>= 1)
        sum += __shfl_down(sum, off);
    if (lane == 0) red[wave] = sum;
    __syncthreads();
    if (tid == 0) {
        float s2 = 0.f;
        #pragma unroll
        for (int w = 0; w < 8; ++w) s2 += red[w];
        atomicAdd(out, s2 * (1.0f / (float)kN));
    }
}

extern "C" void kernel_launch(void* const* d_in, const int* in_sizes, int n_in,
                              void* d_out, int out_size, void* d_ws, size_t ws_size,
                              hipStream_t stream) {
    const float* img     = (const float*)d_in[0];
    const float* txt     = (const float*)d_in[1];
    const float* scale_p = (const float*)d_in[2];
    const float* bias_p  = (const float*)d_in[3];
    float* out = (float*)d_out;

    unsigned char* Af4 = (unsigned char*)d_ws;            // N*KB = 2 MiB
    unsigned char* Bf4 = Af4 + (size_t)kN * KB;           // 2 MiB

    cvt_fp4_kernel<<<dim3(kN * kD / 8 / 256), dim3(256), 0, stream>>>(
        img, txt, (unsigned int*)Af4, (unsigned int*)Bf4, out);
    siglip_gemm_loss_kernel<<<dim3(256), dim3(512), 0, stream>>>(
        Af4, Bf4, scale_p, bias_p, out);
}

// Round 7
// 123.952 us; speedup vs baseline: 1.7895x; 1.7895x over previous
//
#include <hip/hip_runtime.h>
#include <stdint.h>

constexpr int kN = 16384;
constexpr int kD = 256;
constexpr int TM = 256, TN = 256;   // block tile 256x256
constexpr int KB = kD / 2;          // fp4 row = 128 bytes

using floatx16 = __attribute__((ext_vector_type(16))) float;  // 32x32 MFMA C/D
using floatx2  = __attribute__((ext_vector_type(2))) float;   // v_pk_* pair
using intx2v   = __attribute__((ext_vector_type(2))) int;
using intx4    = __attribute__((ext_vector_type(4))) int;
using intx8    = __attribute__((ext_vector_type(8))) int;     // f8f6f4 operand

// fp32*16 -> fp4 e2m1 RNE. Codes 0..7 = {0,.5,1,1.5,2,3,4,6} ARE the bit
// patterns (monotone). Thresholds are the RNE midpoints. (R12-verified.)
__device__ __forceinline__ uint32_t q4(float x) {
    float y = fabsf(x * 16.f);
    uint32_t c = (y >= 0.25f) + (y >= 0.75f) + (y >= 1.25f) + (y >= 1.75f)
               + (y >= 2.5f)  + (y >= 3.5f)  + (y >= 5.0f);
    return c | (x < 0.f ? 8u : 0u);
}

// 8 elems -> one dword per matrix per thread (nibble i = elem 8*idx+i).
// Also zeroes the loss accumulator (replaces the memset dispatch).
__global__ __launch_bounds__(256)
void cvt_fp4_kernel(const float* __restrict__ a, const float* __restrict__ b,
                    unsigned int* __restrict__ oa, unsigned int* __restrict__ ob,
                    float* __restrict__ out) {
    int idx = blockIdx.x * 256 + threadIdx.x;
    if (idx == 0) *out = 0.f;
    float4 a0 = *(const float4*)(a + (size_t)idx * 8);
    float4 a1 = *(const float4*)(a + (size_t)idx * 8 + 4);
    float4 b0 = *(const float4*)(b + (size_t)idx * 8);
    float4 b1 = *(const float4*)(b + (size_t)idx * 8 + 4);
    uint32_t pa = q4(a0.x) | (q4(a0.y) << 4) | (q4(a0.z) << 8)  | (q4(a0.w) << 12)
                | (q4(a1.x) << 16) | (q4(a1.y) << 20) | (q4(a1.z) << 24) | (q4(a1.w) << 28);
    uint32_t pb = q4(b0.x) | (q4(b0.y) << 4) | (q4(b0.z) << 8)  | (q4(b0.w) << 12)
                | (q4(b1.x) << 16) | (q4(b1.y) << 20) | (q4(b1.z) << 24) | (q4(b1.w) << 28);
    oa[idx] = pa;
    ob[idx] = pb;
}

// Undef-high 8-reg tuple from one 4-reg quad: fp4 MFMA reads only v[0:3]
// (HW-validated R14/R15/R19: absmax 0.0).
#define U8(v)  __builtin_shufflevector((v), (v), 0, 1, 2, 3, -1, -1, -1, -1)
#define MFMA4(a, b, c) __builtin_amdgcn_mfma_scale_f32_32x32x64_f8f6f4( \
        (a), (b), (c), 4 /*cbsz fp4*/, 4 /*blgp fp4*/, 0, 127, 0, 127)

// async global->LDS, 16B per lane. LDS dst = wave-uniform base + lane*16
// (hardware rule); global src is per-lane.
__device__ __forceinline__ void gl2lds16(const unsigned char* g, unsigned char* l) {
    __builtin_amdgcn_global_load_lds(
        (const __attribute__((address_space(1))) unsigned int*)g,
        (__attribute__((address_space(3))) unsigned int*)l, 16, 0, 0);
}

// R20: B prefetch moves OUT of the register file. Four spill rounds
// (R14/R16/R17/R19) prove the 2-wave/SIMD budget (256 unified regs) can't
// hold R15's working set (188) + any extra buffering. global_load_lds stages
// B into WAVE-PRIVATE LDS slices (8 waves x 2bufs x 8KB = 128KB): zero VGPRs
// for data, vmcnt-counted depth-1 pipeline (stage s+1 issued at tile-s top,
// s_waitcnt vmcnt(8) -- counted, never 0 mid-loop), and NO barrier in the
// loop (each wave stages exactly the 64 B-rows it reads; 2x redundant B
// traffic across wr, L2-absorbed). Row-major [64][128B] would be a 32-way
// bank conflict on ds_read_b128 (all lanes same 16B column): XOR-swizzle
// physical = L ^ ((row&7)<<4), applied on the pre-swizzled GLOBAL source
// address (LDS dst linear -- guide rule #21) and on the read address.
// z16 dropped (explicit acc=0 init: inline-0 writes, 16 regs saved).
// Budget: af 64 + acc 64 + bl 32 + misc ~30 = ~193 ~= R15's proven 188.
// Gates: (1) WRITE~KB/FETCH 10-16MB no spill; (2) BANK_CONFLICT ~0;
// (3) MfmaUtil 45-60%, GEMM 24-32us.
__global__ __launch_bounds__(512, 2)
void siglip_gemm_loss_kernel(const unsigned char* __restrict__ A,   // fp4 [N][KB]
                             const unsigned char* __restrict__ B,   // fp4 [N][KB]
                             const float* __restrict__ scale_p,
                             const float* __restrict__ bias_p,
                             float* __restrict__ out) {
    __shared__ unsigned char ldsB[8][2][8192];   // [wave][buf][swizzled 64x128B]
    __shared__ float red[8];

    const int tid  = threadIdx.x;
    const int wave = tid >> 6;     // 0..7
    const int lane = tid & 63;

    const int g    = blockIdx.x;                  // 256 persistent blocks
    const int tRow = ((g & 7) << 3) + (g >> 5);   // fixed tile-row (A-stripe L2-hot)
    const int sCol = (g >> 3) & 3;                // tile s -> col sCol + 4s

    const int wr = wave >> 2, wc = wave & 3;   // 2x4 waves
    const int m0 = wr * 128, n0 = wc * 64;     // wave tile 128x64
    const int l31 = lane & 31;
    const int h   = lane >> 5;                 // K-half: byte offset 16h

    const float sc  = *scale_p * (1.0f / 256.0f);   // undo x16 x16 prescale
    const float bs  = *bias_p;
    const float sc3 = sc * (1.44269504f * 8388608.0f);
    const float bs3 = fmaf(bs, 1.44269504f * 8388608.0f, 1064986823.0f);
    const floatx2 sc3v = (floatx2)(sc3);
    const floatx2 bs3v = (floatx2)(bs3);

    // ---- A operand: loop-invariant, resident as raw intx4 quads.
    intx4 af[4][4];
    #pragma unroll
    for (int i = 0; i < 4; ++i) {
        const unsigned char* pa = A + ((size_t)tRow * TM + m0 + i * 32 + l31) * KB + 16 * h;
        #pragma unroll
        for (int q = 0; q < 4; ++q)
            af[i][q] = *(const intx4*)(pa + q * 32);
    }

    floatx16 acc[2][2];     // ONE half-tile of accumulators, reused h0/h1
    floatx2 sm0 = (floatx2)(0.f), sm1 = (floatx2)(0.f);
    float smd = 0.f;        // diagonal correction accumulator

    // ---- B staging addressing.
    // Logical wave slice: 64 rows (n0 + 0..63) x 128 B, contiguous 8KB of B.
    // Physical LDS = logical ^ ((row&7)<<4). Staged with linear LDS dst and
    // swizzled per-lane global src: srcOff(i) = sBase + i*1024, where
    // sBase = (lane*16) ^ (((lane>>3)&7)<<4)  [row = lane>>3 + 8i, row&7 inv].
    const int sBase = (lane * 16) ^ (((lane >> 3) & 7) << 4);
    const unsigned char* pbW = B + (size_t)sCol * TN * KB + (size_t)n0 * KB;

    auto stageT = [&](const int s) {
        const unsigned char* src = pbW + (size_t)s * 4 * TN * KB + sBase;
        unsigned char* dst = &ldsB[wave][s & 1][0];
        #pragma unroll
        for (int i = 0; i < 8; ++i)
            gl2lds16(src + i * 1024, dst + i * 1024);
    };

    // ---- B fragment reads from LDS (swizzled): row r = j*32+l31, col q*32+16h.
    const int rOff0 = l31 * 128;           // j=0 row byte offset
    const int xr    = (l31 & 7) << 4;      // same for both j (j*32 ≡ 0 mod 8)
    intx4 bl[2][4];
    auto ldsLoadT = [&](const int s) {
        const unsigned char* base = &ldsB[wave][s & 1][0];
        #pragma unroll
        for (int j = 0; j < 2; ++j)
            #pragma unroll
            for (int q = 0; q < 4; ++q)
                bl[j][q] = *(const intx4*)(base + rOff0 + j * 4096 +
                                           ((q * 32 + 16 * h) ^ xr));
    };

    // 16 MFMAs of one row-half (rows ibase..ibase+1), acc zero-init inline.
    auto mfmaH = [&](const int ibase) {
        #pragma unroll
        for (int ii = 0; ii < 2; ++ii)
            #pragma unroll
            for (int j = 0; j < 2; ++j) acc[ii][j] = (floatx16)(0.f);
        #pragma unroll
        for (int q = 0; q < 4; ++q)
            #pragma unroll
            for (int ii = 0; ii < 2; ++ii) {
                const intx8 a = U8(af[ibase + ii][q]);
                #pragma unroll
                for (int j = 0; j < 2; ++j)
                    acc[ii][j] = MFMA4(a, U8(bl[j][q]), acc[ii][j]);
            }
    };

    // Schraudolph epilogue of one half (64 elems), packed 2-wide.
    auto epiH = [&](const int ibase, const int tCol) {
        #pragma unroll
        for (int ii = 0; ii < 2; ++ii)
            #pragma unroll
            for (int j = 0; j < 2; ++j) {
                const floatx16 a = acc[ii][j];
                #pragma unroll
                for (int v = 0; v < 16; v += 4) {
                    floatx2 t0 = {a[v + 0], a[v + 1]};
                    floatx2 t1 = {a[v + 2], a[v + 3]};
                    t0 = __builtin_elementwise_fma(t0, sc3v, bs3v);  // v_pk_fma_f32
                    t1 = __builtin_elementwise_fma(t1, sc3v, bs3v);
                    const intx2v e0 = {(int)t0.x, (int)t0.y};        // v_cvt_i32_f32
                    const intx2v e1 = {(int)t1.x, (int)t1.y};
                    sm0 += __builtin_bit_cast(floatx2, e0);          // v_pk_add_f32
                    sm1 += __builtin_bit_cast(floatx2, e1);
                }
                // diagonal correction: term_diag = term_off - t
                const int gRow0 = tRow * TM + m0 + (ibase + ii) * 32;
                const int gCol0 = tCol * TN + n0 + j * 32;
                if (gRow0 == gCol0) {   // wave-uniform, rare
                    #pragma unroll
                    for (int v = 0; v < 16; ++v) {
                        const int rrow = (v & 3) + 8 * (v >> 2) + 4 * h;
                        if (rrow == l31) smd += fmaf(a[v], sc, bs);
                    }
                }
            }
    };

    // ---- main loop: barrier-free, vmcnt-counted depth-1 LDS pipeline.
    stageT(0);
    // SIMD-mates are waves w and w+4 (wr 0/1): anti-phase their E/M phases.
    if (wr) __builtin_amdgcn_s_sleep(10);
    for (int s = 0; s < 16; ++s) {
        if (s < 15) {
            stageT(s + 1);                                   // 8 in flight
            asm volatile("s_waitcnt vmcnt(8)" ::: "memory"); // stage(s) landed
        } else {
            asm volatile("s_waitcnt vmcnt(0)" ::: "memory");
        }
        ldsLoadT(s);                    // 8 ds_read_b128 (latency under epi)
        if (s > 0) epiH(2, sCol + 4 * (s - 1));   // E h1(s-1)
        mfmaH(0);                       // M h0(s)
        epiH(0, sCol + 4 * s);          // E h0(s)
        mfmaH(2);                       // M h1(s)
    }
    epiH(2, sCol + 60);                 // drain tile 15 h1

    float sum = (sm0.x + sm1.x) + (sm0.y + sm1.y) - smd;

    // block reduce -> ONE atomicAdd per block (256 total, spread in time)
    #pragma unroll
    for (int off = 32; off > 0; off >>= 1)
        sum += __shfl_down(sum, off);
    if (lane == 0) red[wave] = sum;
    __syncthreads();
    if (tid == 0) {
        float s2 = 0.f;
        #pragma unroll
        for (int w = 0; w < 8; ++w) s2 += red[w];
        atomicAdd(out, s2 * (1.0f / (float)kN));
    }
}

extern "C" void kernel_launch(void* const* d_in, const int* in_sizes, int n_in,
                              void* d_out, int out_size, void* d_ws, size_t ws_size,
                              hipStream_t stream) {
    const float* img     = (const float*)d_in[0];
    const float* txt     = (const float*)d_in[1];
    const float* scale_p = (const float*)d_in[2];
    const float* bias_p  = (const float*)d_in[3];
    float* out = (float*)d_out;

    unsigned char* Af4 = (unsigned char*)d_ws;            // N*KB = 2 MiB
    unsigned char* Bf4 = Af4 + (size_t)kN * KB;           // 2 MiB

    cvt_fp4_kernel<<<dim3(kN * kD / 8 / 256), dim3(256), 0, stream>>>(
        img, txt, (unsigned int*)Af4, (unsigned int*)Bf4, out);
    siglip_gemm_loss_kernel<<<dim3(256), dim3(512), 0, stream>>>(
        Af4, Bf4, scale_p, bias_p, out);
}

// Round 8
// 121.316 us; speedup vs baseline: 1.8284x; 1.0217x over previous
//
#include <hip/hip_runtime.h>
#include <stdint.h>

constexpr int kN = 16384;
constexpr int kD = 256;
constexpr int TM = 256, TN = 256;   // block tile 256x256
constexpr int KB = kD / 2;          // fp4 row = 128 bytes

using floatx16 = __attribute__((ext_vector_type(16))) float;  // 32x32 MFMA C/D
using floatx2  = __attribute__((ext_vector_type(2))) float;   // v_pk_* pair
using intx2v   = __attribute__((ext_vector_type(2))) int;
using intx4    = __attribute__((ext_vector_type(4))) int;
using intx8    = __attribute__((ext_vector_type(8))) int;     // f8f6f4 operand

// fp32*16 -> fp4 e2m1 RNE. Codes 0..7 = {0,.5,1,1.5,2,3,4,6} ARE the bit
// patterns (monotone). Thresholds are the RNE midpoints. (R12-verified.)
__device__ __forceinline__ uint32_t q4(float x) {
    float y = fabsf(x * 16.f);
    uint32_t c = (y >= 0.25f) + (y >= 0.75f) + (y >= 1.25f) + (y >= 1.75f)
               + (y >= 2.5f)  + (y >= 3.5f)  + (y >= 5.0f);
    return c | (x < 0.f ? 8u : 0u);
}

// 8 elems -> one dword per thread. A stays row-major. B is written
// CHUNK-MAJOR: B'[c][row] with c = 16B K-chunk (32 fp4 elems), i.e. dword
// address (c*kN + row)*4 + w. This makes the GEMM's LDS staging coalesced
// AND its ds_read_b128 pattern bank-conflict-free (R20's [row][col] layout
// forced a 4-way conflict: 16B-column reads of 32 rows).
__global__ __launch_bounds__(256)
void cvt_fp4_kernel(const float* __restrict__ a, const float* __restrict__ b,
                    unsigned int* __restrict__ oa, unsigned int* __restrict__ ob,
                    float* __restrict__ out) {
    int idx = blockIdx.x * 256 + threadIdx.x;
    if (idx == 0) *out = 0.f;
    float4 a0 = *(const float4*)(a + (size_t)idx * 8);
    float4 a1 = *(const float4*)(a + (size_t)idx * 8 + 4);
    float4 b0 = *(const float4*)(b + (size_t)idx * 8);
    float4 b1 = *(const float4*)(b + (size_t)idx * 8 + 4);
    uint32_t pa = q4(a0.x) | (q4(a0.y) << 4) | (q4(a0.z) << 8)  | (q4(a0.w) << 12)
                | (q4(a1.x) << 16) | (q4(a1.y) << 20) | (q4(a1.z) << 24) | (q4(a1.w) << 28);
    uint32_t pb = q4(b0.x) | (q4(b0.y) << 4) | (q4(b0.z) << 8)  | (q4(b0.w) << 12)
                | (q4(b1.x) << 16) | (q4(b1.y) << 20) | (q4(b1.z) << 24) | (q4(b1.w) << 28);
    oa[idx] = pa;
    const int row = idx >> 5, d = idx & 31, c = d >> 2, w = d & 3;
    ob[((size_t)c * kN + row) * 4 + w] = pb;
}

// Undef-high 8-reg tuple from one 4-reg quad: fp4 MFMA reads only v[0:3]
// (HW-validated R14/R15/R19/R20: absmax 0.0).
#define U8(v)  __builtin_shufflevector((v), (v), 0, 1, 2, 3, -1, -1, -1, -1)
#define MFMA4(a, b, c) __builtin_amdgcn_mfma_scale_f32_32x32x64_f8f6f4( \
        (a), (b), (c), 4 /*cbsz fp4*/, 4 /*blgp fp4*/, 0, 127, 0, 127)

// async global->LDS, 16B per lane. LDS dst = wave-uniform base + lane*16.
__device__ __forceinline__ void gl2lds16(const unsigned char* g, unsigned char* l) {
    __builtin_amdgcn_global_load_lds(
        (const __attribute__((address_space(1))) unsigned int*)g,
        (__attribute__((address_space(3))) unsigned int*)l, 16, 0, 0);
}

// R21: slot-granular in-wave interleave on top of LDS-staged chunk-major B.
// R20 post-mortem: VALU (50k cy/SIMD) > MFMA (36k floor); phase-separated
// 2-wave structure pinned at 25-29% MfmaUtil for 3 rounds; 4-way LDS bank
// conflict (1.05M); acc-in-AGPR epi copies + 128 zero-init movs/tile.
// Fixes: (a) chunk-major B -> conflict-free contiguous ds_reads, ~zero
// addressing VALU (1 base reg + imm offsets), coalesced staging; (b) R17's
// slot ping-pong (slot = one 32x32 output block, 4 chained full-K MFMAs into
// accA/accB alternating; previous slot's 32-inst epilogue interleaved 1:8
// between MFMAs -> epi VALU rides in MFMA dep-latency gaps) -- now fits:
// af 64 + bl 32 + accA/B 32 + z16 16 + misc ~36 = ~180 < 256 (B dbuf lives
// in LDS, not regs -- R17's spill source removed); (c) z16 restored.
// Gates: (1) WRITE ~10KB (no spill); (2) BANK_CONFLICT ~0;
// (3) MfmaUtil 50-70%, GEMM 18-26us.
__global__ __launch_bounds__(512, 2)
void siglip_gemm_loss_kernel(const unsigned char* __restrict__ A,   // fp4 [N][KB]
                             const unsigned char* __restrict__ Bc,  // fp4 chunk-major
                             const float* __restrict__ scale_p,
                             const float* __restrict__ bias_p,
                             float* __restrict__ out) {
    __shared__ unsigned char ldsB[8][2][8192];   // [wave][buf][chunk-major 8x64x16B]
    __shared__ float red[8];

    const int tid  = threadIdx.x;
    const int wave = tid >> 6;     // 0..7
    const int lane = tid & 63;

    const int g    = blockIdx.x;                  // 256 persistent blocks
    const int tRow = ((g & 7) << 3) + (g >> 5);   // fixed tile-row (A-stripe L2-hot)
    const int sCol = (g >> 3) & 3;                // tile s -> col sCol + 4s

    const int wr = wave >> 2, wc = wave & 3;   // 2x4 waves
    const int m0 = wr * 128, n0 = wc * 64;     // wave tile 128x64
    const int l31 = lane & 31;
    const int h   = lane >> 5;                 // K-half: byte offset 16h

    const float sc  = *scale_p * (1.0f / 256.0f);   // undo x16 x16 prescale
    const float bs  = *bias_p;
    const float sc3 = sc * (1.44269504f * 8388608.0f);
    const float bs3 = fmaf(bs, 1.44269504f * 8388608.0f, 1064986823.0f);
    const floatx2 sc3v = (floatx2)(sc3);
    const floatx2 bs3v = (floatx2)(bs3);

    // ---- A operand: loop-invariant, resident as raw intx4 quads (row-major A).
    intx4 af[4][4];
    #pragma unroll
    for (int i = 0; i < 4; ++i) {
        const unsigned char* pa = A + ((size_t)tRow * TM + m0 + i * 32 + l31) * KB + 16 * h;
        #pragma unroll
        for (int q = 0; q < 4; ++q)
            af[i][q] = *(const intx4*)(pa + q * 32);
    }

    const floatx16 z16 = (floatx16)(0.f);   // C operand of each slot's first MFMA

    floatx16 accA, accB;            // ping-pong slot accumulators (16 regs each)
    floatx2 sm0 = (floatx2)(0.f), sm1 = (floatx2)(0.f);
    float smd = 0.f;                // diagonal correction accumulator

    // ---- staging: chunk i (16B of K) for the wave's 64 B-rows.
    // src contiguous 1024B per instruction (chunk-major global), dst linear.
    const unsigned char* pSrcLane =
        Bc + ((size_t)(sCol * TN + n0) + lane) * 16;
    auto stageT = [&](const int s) {
        const unsigned char* src = pSrcLane + (size_t)s * (4 * TN * 16);
        unsigned char* dst = &ldsB[wave][s & 1][0];
        #pragma unroll
        for (int i = 0; i < 8; ++i)
            gl2lds16(src + (size_t)i * (kN * 16), dst + i * 1024);
    };

    // ---- B tile read: quad (j,q) = chunk c=2q+h, row j*32+l31.
    // addr = (2q+h)*1024 + (j*32+l31)*16 = [h*1024 + l31*16] + q*2048 + j*512.
    // Lanes h=0: contiguous 512B; h=1: contiguous 512B -> zero bank conflicts.
    intx4 bl[2][4];
    auto ldsLoadT = [&](const int s) {
        const unsigned char* base = &ldsB[wave][s & 1][h * 1024 + l31 * 16];
        #pragma unroll
        for (int j = 0; j < 2; ++j)
            #pragma unroll
            for (int q = 0; q < 4; ++q)
                bl[j][q] = *(const intx4*)(base + q * 2048 + j * 512);
    };

    // one epi slice: 4 elems of ae starting at vb (2 pk_fma + 4 cvt + 2 pk_add)
    auto epiQ = [&](const floatx16& ae, const int vb) {
        floatx2 t0 = {ae[vb + 0], ae[vb + 1]};
        floatx2 t1 = {ae[vb + 2], ae[vb + 3]};
        t0 = __builtin_elementwise_fma(t0, sc3v, bs3v);  // v_pk_fma_f32
        t1 = __builtin_elementwise_fma(t1, sc3v, bs3v);
        const intx2v e0 = {(int)t0.x, (int)t0.y};        // v_cvt_i32_f32
        const intx2v e1 = {(int)t1.x, (int)t1.y};
        sm0 += __builtin_bit_cast(floatx2, e0);          // v_pk_add_f32
        sm1 += __builtin_bit_cast(floatx2, e1);
    };

    // diagonal correction for one epilogued slot (wave-uniform, rare)
    auto epiDiag1 = [&](const floatx16& ae, const int iE, const int jE,
                        const int tColE) {
        const int gRow0 = tRow * TM + m0 + iE * 32;
        const int gCol0 = tColE * TN + n0 + jE * 32;
        if (gRow0 == gCol0) {
            #pragma unroll
            for (int v = 0; v < 16; ++v) {
                const int rrow = (v & 3) + 8 * (v >> 2) + 4 * h;
                if (rrow == l31) smd += fmaf(ae[v], sc, bs);
            }
        }
    };

    // one slot: output block (ii,j), 4 chained full-K MFMAs into aw; previous
    // slot's epilogue (ae, other buffer) interleaved into the dep-stall gaps.
    auto slotStep = [&](floatx16& aw, const floatx16& ae, const int ii,
                        const int j, const bool doEpi, const int iE,
                        const int jE, const int tColE) {
        aw = MFMA4(U8(af[ii][0]), U8(bl[j][0]), z16);
        if (doEpi) epiQ(ae, 0);
        aw = MFMA4(U8(af[ii][1]), U8(bl[j][1]), aw);
        if (doEpi) epiQ(ae, 4);
        aw = MFMA4(U8(af[ii][2]), U8(bl[j][2]), aw);
        if (doEpi) epiQ(ae, 8);
        aw = MFMA4(U8(af[ii][3]), U8(bl[j][3]), aw);
        if (doEpi) { epiQ(ae, 12); epiDiag1(ae, iE, jE, tColE); }
    };

    // ---- main loop: barrier-free, vmcnt-counted depth-1 LDS pipeline.
    stageT(0);
    for (int s = 0; s < 16; ++s) {
        if (s < 15) {
            stageT(s + 1);                                   // 8 more in flight
            asm volatile("s_waitcnt vmcnt(8)" ::: "memory"); // stage(s) landed
        } else {
            asm volatile("s_waitcnt vmcnt(0)" ::: "memory");
        }
        ldsLoadT(s);                // 8 ds_read_b128, conflict-free
        const int c  = sCol + 4 * s;
        const int cP = c - 4;
        slotStep(accA, accB, 0, 0, s > 0, 3, 1, cP);  // epis prev tile slot 7
        slotStep(accB, accA, 0, 1, true, 0, 0, c);
        slotStep(accA, accB, 1, 0, true, 0, 1, c);
        slotStep(accB, accA, 1, 1, true, 1, 0, c);
        slotStep(accA, accB, 2, 0, true, 1, 1, c);
        slotStep(accB, accA, 2, 1, true, 2, 0, c);
        slotStep(accA, accB, 3, 0, true, 2, 1, c);
        slotStep(accB, accA, 3, 1, true, 3, 0, c);
    }
    // drain tile 15 slot 7 (sits in accB)
    #pragma unroll
    for (int vb = 0; vb < 16; vb += 4) epiQ(accB, vb);
    epiDiag1(accB, 3, 1, sCol + 60);

    float sum = (sm0.x + sm1.x) + (sm0.y + sm1.y) - smd;

    // block reduce -> ONE atomicAdd per block (256 total, spread in time)
    #pragma unroll
    for (int off = 32; off > 0; off >>= 1)
        sum += __shfl_down(sum, off);
    if (lane == 0) red[wave] = sum;
    __syncthreads();
    if (tid == 0) {
        float s2 = 0.f;
        #pragma unroll
        for (int w = 0; w < 8; ++w) s2 += red[w];
        atomicAdd(out, s2 * (1.0f / (float)kN));
    }
}

extern "C" void kernel_launch(void* const* d_in, const int* in_sizes, int n_in,
                              void* d_out, int out_size, void* d_ws, size_t ws_size,
                              hipStream_t stream) {
    const float* img     = (const float*)d_in[0];
    const float* txt     = (const float*)d_in[1];
    const float* scale_p = (const float*)d_in[2];
    const float* bias_p  = (const float*)d_in[3];
    float* out = (float*)d_out;

    unsigned char* Af4 = (unsigned char*)d_ws;            // N*KB = 2 MiB (row-major)
    unsigned char* Bf4 = Af4 + (size_t)kN * KB;           // 2 MiB (chunk-major)

    cvt_fp4_kernel<<<dim3(kN * kD / 8 / 256), dim3(256), 0, stream>>>(
        img, txt, (unsigned int*)Af4, (unsigned int*)Bf4, out);
    siglip_gemm_loss_kernel<<<dim3(256), dim3(512), 0, stream>>>(
        Af4, Bf4, scale_p, bias_p, out);
}

// Round 9
// 119.556 us; speedup vs baseline: 1.8553x; 1.0147x over previous
//
#include <hip/hip_runtime.h>
#include <stdint.h>

constexpr int kN = 16384;
constexpr int kD = 256;
constexpr int TM = 256, TN = 256;   // block tile 256x256
constexpr int KB = kD / 2;          // fp4 row = 128 bytes

using floatx16 = __attribute__((ext_vector_type(16))) float;  // 32x32 MFMA C/D
using floatx2  = __attribute__((ext_vector_type(2))) float;   // v_pk_* pair
using intx2v   = __attribute__((ext_vector_type(2))) int;
using intx4    = __attribute__((ext_vector_type(4))) int;
using intx8    = __attribute__((ext_vector_type(8))) int;     // f8f6f4 operand

// fp32*16 -> fp4 e2m1 RNE. Codes 0..7 = {0,.5,1,1.5,2,3,4,6} ARE the bit
// patterns (monotone). Thresholds are the RNE midpoints. (R12-verified.)
__device__ __forceinline__ uint32_t q4(float x) {
    float y = fabsf(x * 16.f);
    uint32_t c = (y >= 0.25f) + (y >= 0.75f) + (y >= 1.25f) + (y >= 1.75f)
               + (y >= 2.5f)  + (y >= 3.5f)  + (y >= 5.0f);
    return c | (x < 0.f ? 8u : 0u);
}

// 8 elems -> one dword per thread. A row-major; B CHUNK-MAJOR B'[c][row]
// (c = 16B K-chunk) -> GEMM staging coalesced + ds_reads conflict-free
// (R21-verified: SQ_LDS_BANK_CONFLICT = 0).
__global__ __launch_bounds__(256)
void cvt_fp4_kernel(const float* __restrict__ a, const float* __restrict__ b,
                    unsigned int* __restrict__ oa, unsigned int* __restrict__ ob,
                    float* __restrict__ out) {
    int idx = blockIdx.x * 256 + threadIdx.x;
    if (idx == 0) *out = 0.f;
    float4 a0 = *(const float4*)(a + (size_t)idx * 8);
    float4 a1 = *(const float4*)(a + (size_t)idx * 8 + 4);
    float4 b0 = *(const float4*)(b + (size_t)idx * 8);
    float4 b1 = *(const float4*)(b + (size_t)idx * 8 + 4);
    uint32_t pa = q4(a0.x) | (q4(a0.y) << 4) | (q4(a0.z) << 8)  | (q4(a0.w) << 12)
                | (q4(a1.x) << 16) | (q4(a1.y) << 20) | (q4(a1.z) << 24) | (q4(a1.w) << 28);
    uint32_t pb = q4(b0.x) | (q4(b0.y) << 4) | (q4(b0.z) << 8)  | (q4(b0.w) << 12)
                | (q4(b1.x) << 16) | (q4(b1.y) << 20) | (q4(b1.z) << 24) | (q4(b1.w) << 28);
    oa[idx] = pa;
    const int row = idx >> 5, d = idx & 31, c = d >> 2, w = d & 3;
    ob[((size_t)c * kN + row) * 4 + w] = pb;
}

// Undef-high 8-reg tuple from one 4-reg quad: fp4 MFMA reads only v[0:3]
// (HW-validated R14/R15/R19/R20/R21: absmax 0.0).
#define U8(v)  __builtin_shufflevector((v), (v), 0, 1, 2, 3, -1, -1, -1, -1)
#define MFMA4(a, b, c) __builtin_amdgcn_mfma_scale_f32_32x32x64_f8f6f4( \
        (a), (b), (c), 4 /*cbsz fp4*/, 4 /*blgp fp4*/, 0, 127, 0, 127)
// sched_group_barrier masks (m137-verified): MFMA=0x8, VALU=0x2
#define SGB __builtin_amdgcn_sched_group_barrier

// async global->LDS, 16B per lane. LDS dst = wave-uniform base + lane*16.
__device__ __forceinline__ void gl2lds16(const unsigned char* g, unsigned char* l) {
    __builtin_amdgcn_global_load_lds(
        (const __attribute__((address_space(1))) unsigned int*)g,
        (__attribute__((address_space(3))) unsigned int*)l, 16, 0, 0);
}

// R22: compile-time-pinned 1:8 MFMA:VALU interleave. R21 passed every
// hygiene gate (0 conflicts, 0 spill, VGPR 120) yet MfmaUtil stayed 27%,
// and across R13/R15/R20/R21 MfmaUtil+VALUBusy = 68-81%, NEVER >100%:
// the two pipes are serialized even though HW overlaps them across waves
// (m114). Cause: hipcc re-clusters the source interleave into MFMA-blocks
// and VALU-blocks (it preserves deps, not order), and 2 same-code waves
// self-lock into the same phase -> both pipes take turns idling.
// Fix: __builtin_amdgcn_sched_group_barrier pins each slot's emitted order
// to MFMA,8xVALU,MFMA,8xVALU,... -> each wave's epi VALU fills its own
// MFMA dep-stall slots; at 35-cy granularity wave phasing stops mattering.
// Overlap proof criterion: MfmaUtil+VALUBusy > 100%.
__global__ __launch_bounds__(512, 2)
void siglip_gemm_loss_kernel(const unsigned char* __restrict__ A,   // fp4 [N][KB]
                             const unsigned char* __restrict__ Bc,  // fp4 chunk-major
                             const float* __restrict__ scale_p,
                             const float* __restrict__ bias_p,
                             float* __restrict__ out) {
    __shared__ unsigned char ldsB[8][2][8192];   // [wave][buf][chunk-major 8x64x16B]
    __shared__ float red[8];

    const int tid  = threadIdx.x;
    const int wave = tid >> 6;     // 0..7
    const int lane = tid & 63;

    const int g    = blockIdx.x;                  // 256 persistent blocks
    const int tRow = ((g & 7) << 3) + (g >> 5);   // fixed tile-row (A-stripe L2-hot)
    const int sCol = (g >> 3) & 3;                // tile s -> col sCol + 4s

    const int wr = wave >> 2, wc = wave & 3;   // 2x4 waves
    const int m0 = wr * 128, n0 = wc * 64;     // wave tile 128x64
    const int l31 = lane & 31;
    const int h   = lane >> 5;                 // K-half: byte offset 16h

    const float sc  = *scale_p * (1.0f / 256.0f);   // undo x16 x16 prescale
    const float bs  = *bias_p;
    const float sc3 = sc * (1.44269504f * 8388608.0f);
    const float bs3 = fmaf(bs, 1.44269504f * 8388608.0f, 1064986823.0f);
    const floatx2 sc3v = (floatx2)(sc3);
    const floatx2 bs3v = (floatx2)(bs3);

    // ---- A operand: loop-invariant, resident as raw intx4 quads (row-major A).
    intx4 af[4][4];
    #pragma unroll
    for (int i = 0; i < 4; ++i) {
        const unsigned char* pa = A + ((size_t)tRow * TM + m0 + i * 32 + l31) * KB + 16 * h;
        #pragma unroll
        for (int q = 0; q < 4; ++q)
            af[i][q] = *(const intx4*)(pa + q * 32);
    }

    const floatx16 z16 = (floatx16)(0.f);   // C operand of each slot's first MFMA

    floatx16 accA, accB;            // ping-pong slot accumulators (16 regs each)
    floatx2 sm0 = (floatx2)(0.f), sm1 = (floatx2)(0.f);
    float smd = 0.f;                // diagonal correction accumulator

    // ---- staging: chunk i (16B of K) for the wave's 64 B-rows.
    const unsigned char* pSrcLane =
        Bc + ((size_t)(sCol * TN + n0) + lane) * 16;
    auto stageT = [&](const int s) {
        const unsigned char* src = pSrcLane + (size_t)s * (4 * TN * 16);
        unsigned char* dst = &ldsB[wave][s & 1][0];
        #pragma unroll
        for (int i = 0; i < 8; ++i)
            gl2lds16(src + (size_t)i * (kN * 16), dst + i * 1024);
    };

    // ---- B tile read: quad (j,q) = chunk c=2q+h, row j*32+l31.
    intx4 bl[2][4];
    auto ldsLoadT = [&](const int s) {
        const unsigned char* base = &ldsB[wave][s & 1][h * 1024 + l31 * 16];
        #pragma unroll
        for (int j = 0; j < 2; ++j)
            #pragma unroll
            for (int q = 0; q < 4; ++q)
                bl[j][q] = *(const intx4*)(base + q * 2048 + j * 512);
    };

    // one epi slice: 4 elems of ae starting at vb = exactly 8 VALU
    // (2 pk_fma + 4 cvt + 2 pk_add) -> matches the SGB VALU group size.
    auto epiQ = [&](const floatx16& ae, const int vb) {
        floatx2 t0 = {ae[vb + 0], ae[vb + 1]};
        floatx2 t1 = {ae[vb + 2], ae[vb + 3]};
        t0 = __builtin_elementwise_fma(t0, sc3v, bs3v);  // v_pk_fma_f32
        t1 = __builtin_elementwise_fma(t1, sc3v, bs3v);
        const intx2v e0 = {(int)t0.x, (int)t0.y};        // v_cvt_i32_f32
        const intx2v e1 = {(int)t1.x, (int)t1.y};
        sm0 += __builtin_bit_cast(floatx2, e0);          // v_pk_add_f32
        sm1 += __builtin_bit_cast(floatx2, e1);
    };

    // diagonal correction for one epilogued slot (wave-uniform, rare).
    // Branchy: kept OUTSIDE the SGB-pinned straight-line region.
    auto epiDiag1 = [&](const floatx16& ae, const int iE, const int jE,
                        const int tColE) {
        const int gRow0 = tRow * TM + m0 + iE * 32;
        const int gCol0 = tColE * TN + n0 + jE * 32;
        if (gRow0 == gCol0) {
            #pragma unroll
            for (int v = 0; v < 16; ++v) {
                const int rrow = (v & 3) + 8 * (v >> 2) + 4 * h;
                if (rrow == l31) smd += fmaf(ae[v], sc, bs);
            }
        }
    };

    // one slot: output block (ii,j), 4 chained full-K MFMAs into aw; previous
    // slot's epilogue (ae, other buffer) interleaved 1 MFMA : 8 VALU, and the
    // interleave PINNED into the emitted code via sched_group_barrier.
    auto slotStep = [&](floatx16& aw, const floatx16& ae, const int ii,
                        const int j, const bool doEpi, const int iE,
                        const int jE, const int tColE) {
        aw = MFMA4(U8(af[ii][0]), U8(bl[j][0]), z16);
        if (doEpi) epiQ(ae, 0);
        aw = MFMA4(U8(af[ii][1]), U8(bl[j][1]), aw);
        if (doEpi) epiQ(ae, 4);
        aw = MFMA4(U8(af[ii][2]), U8(bl[j][2]), aw);
        if (doEpi) epiQ(ae, 8);
        aw = MFMA4(U8(af[ii][3]), U8(bl[j][3]), aw);
        if (doEpi) {
            epiQ(ae, 12);
            // pin emitted order for this region: MFMA,8V,MFMA,8V,MFMA,8V,MFMA,8V
            #pragma unroll
            for (int k = 0; k < 4; ++k) {
                SGB(0x008, 1, 0);   // 1 MFMA
                SGB(0x002, 8, 0);   // 8 VALU
            }
            epiDiag1(ae, iE, jE, tColE);
        }
    };

    // ---- main loop: barrier-free, vmcnt-counted depth-1 LDS pipeline.
    stageT(0);
    for (int s = 0; s < 16; ++s) {
        if (s < 15) {
            stageT(s + 1);                                   // 8 more in flight
            asm volatile("s_waitcnt vmcnt(8)" ::: "memory"); // stage(s) landed
        } else {
            asm volatile("s_waitcnt vmcnt(0)" ::: "memory");
        }
        ldsLoadT(s);                // 8 ds_read_b128, conflict-free
        const int c  = sCol + 4 * s;
        const int cP = c - 4;
        slotStep(accA, accB, 0, 0, s > 0, 3, 1, cP);  // epis prev tile slot 7
        slotStep(accB, accA, 0, 1, true, 0, 0, c);
        slotStep(accA, accB, 1, 0, true, 0, 1, c);
        slotStep(accB, accA, 1, 1, true, 1, 0, c);
        slotStep(accA, accB, 2, 0, true, 1, 1, c);
        slotStep(accB, accA, 2, 1, true, 2, 0, c);
        slotStep(accA, accB, 3, 0, true, 2, 1, c);
        slotStep(accB, accA, 3, 1, true, 3, 0, c);
    }
    // drain tile 15 slot 7 (sits in accB)
    #pragma unroll
    for (int vb = 0; vb < 16; vb += 4) epiQ(accB, vb);
    epiDiag1(accB, 3, 1, sCol + 60);

    float sum = (sm0.x + sm1.x) + (sm0.y + sm1.y) - smd;

    // block reduce -> ONE atomicAdd per block (256 total, spread in time)
    #pragma unroll
    for (int off = 32; off > 0; off >>= 1)
        sum += __shfl_down(sum, off);
    if (lane == 0) red[wave] = sum;
    __syncthreads();
    if (tid == 0) {
        float s2 = 0.f;
        #pragma unroll
        for (int w = 0; w < 8; ++w) s2 += red[w];
        atomicAdd(out, s2 * (1.0f / (float)kN));
    }
}

extern "C" void kernel_launch(void* const* d_in, const int* in_sizes, int n_in,
                              void* d_out, int out_size, void* d_ws, size_t ws_size,
                              hipStream_t stream) {
    const float* img     = (const float*)d_in[0];
    const float* txt     = (const float*)d_in[1];
    const float* scale_p = (const float*)d_in[2];
    const float* bias_p  = (const float*)d_in[3];
    float* out = (float*)d_out;

    unsigned char* Af4 = (unsigned char*)d_ws;            // N*KB = 2 MiB (row-major)
    unsigned char* Bf4 = Af4 + (size_t)kN * KB;           // 2 MiB (chunk-major)

    cvt_fp4_kernel<<<dim3(kN * kD / 8 / 256), dim3(256), 0, stream>>>(
        img, txt, (unsigned int*)Af4, (unsigned int*)Bf4, out);
    siglip_gemm_loss_kernel<<<dim3(256), dim3(512), 0, stream>>>(
        Af4, Bf4, scale_p, bias_p, out);
}